// Round 5
// baseline (246.251 us; speedup 1.0000x reference)
//
#include <hip/hip_runtime.h>

#define BSZ 64
#define LMAX 128
#define DIM 2048

struct Ctrl {
    float accum;     // loss sum
    int   count;     // valid-pair count
    int   done2;     // finished loss-blocks
    int   pad;
    int   done[BSZ]; // finished proj-blocks per batch
};

// ---- single fused kernel: proj + per-batch loss (last-block) + finalize ----
// 1024 blocks x 512 threads; 8 waves/block, 1 position/wave; 16 blocks/batch.
// LDS: 32 KB W stage + 2 KB proj stage -> 4 blocks/CU = 32 waves/CU.
__global__ __launch_bounds__(512) void fused_kernel(
        const float* __restrict__ enc,
        const float* __restrict__ W,
        const int* __restrict__ mask,
        const float* __restrict__ bias,
        float* __restrict__ proj,
        Ctrl* __restrict__ ctrl,
        float* __restrict__ out) {
    __shared__ float4 sW[4][512];
    __shared__ float4 s_proj[LMAX];
    __shared__ float  s_w[8];
    __shared__ int    s_m[8];
    __shared__ int    s_last;

    const int tid  = threadIdx.x;
    const int wid  = tid >> 6;
    const int lane = tid & 63;
    const int p    = blockIdx.x * 8 + wid;   // position 0..8191
    const int b    = blockIdx.x >> 4;        // batch 0..63

    // stage W once per block (broadcast, L2/L3-hot)
    const float4* __restrict__ W4 = (const float4*)W;
    sW[0][tid] = W4[tid * 2];
    sW[1][tid] = W4[tid * 2 + 1];
    sW[2][tid] = W4[1024 + tid * 2];
    sW[3][tid] = W4[1024 + tid * 2 + 1];
    __syncthreads();

    // ---- proj phase: one 2048-dim dot x4 per wave ----
    const float4* __restrict__ h4 = (const float4*)(enc + (size_t)p * DIM);
    float a0 = 0.f, a1 = 0.f, a2 = 0.f, a3 = 0.f;
    #pragma unroll
    for (int it = 0; it < 8; ++it) {
        const int idx = it * 64 + lane;
        const float4 h  = h4[idx];
        const float4 w0 = sW[0][idx];
        const float4 w1 = sW[1][idx];
        const float4 w2 = sW[2][idx];
        const float4 w3 = sW[3][idx];
        a0 += h.x * w0.x + h.y * w0.z + h.z * w1.x + h.w * w1.z;
        a1 += h.x * w0.y + h.y * w0.w + h.z * w1.y + h.w * w1.w;
        a2 += h.x * w2.x + h.y * w2.z + h.z * w3.x + h.w * w3.z;
        a3 += h.x * w2.y + h.y * w2.w + h.z * w3.y + h.w * w3.w;
    }
    #pragma unroll
    for (int off = 32; off >= 1; off >>= 1) {
        a0 += __shfl_xor(a0, off);
        a1 += __shfl_xor(a1, off);
        a2 += __shfl_xor(a2, off);
        a3 += __shfl_xor(a3, off);
    }
    if (lane == 0) {
        float4 v; v.x = a0; v.y = a1; v.z = a2; v.w = a3;
        ((float4*)proj)[p] = v;
    }

    // ---- release our proj writes, claim batch-completion ticket ----
    __threadfence();            // device-scope release (all threads)
    __syncthreads();
    if (tid == 0) {
        const int prev = atomicAdd(&ctrl->done[b], 1);
        s_last = (prev == 15);
    }
    __syncthreads();
    if (!s_last) return;

    // ---- loss phase: this block owns batch b; all 16 proj blocks done ----
    __threadfence();            // device-scope acquire
    if (tid < LMAX) s_proj[tid] = ((const float4*)proj)[b * LMAX + tid];

    int m = (tid < LMAX) ? mask[b * LMAX + tid] : 0;
    #pragma unroll
    for (int off = 32; off >= 1; off >>= 1) m += __shfl_xor(m, off);
    if (lane == 0) s_m[wid] = m;
    __syncthreads();

    int T = 0;
    #pragma unroll
    for (int w = 0; w < 8; ++w) T += s_m[w];
    const float b0 = bias[0];
    const float b1 = bias[1];

    float local = 0.f;
    const int tmax = T << 7;
    for (int t = tid; t < tmax; t += 512) {
        const int j = t >> 7;
        const int k = t & (LMAX - 1);
        if (k < j) {
            const float4 pj = s_proj[j];
            const float4 pk = s_proj[k];
            const float l0 = pj.x + pk.z + b0;
            const float l1 = pj.y + pk.w + b1;
            const bool  pos = (k == j - 1);
            const float d  = pos ? (l0 - l1) : (l1 - l0);
            local += fmaxf(d, 0.f) + __logf(1.f + __expf(-fabsf(d)));
        }
    }
    #pragma unroll
    for (int off = 32; off >= 1; off >>= 1) local += __shfl_xor(local, off);
    if (lane == 0) s_w[wid] = local;
    __syncthreads();

    if (tid == 0) {
        float s = 0.f;
        #pragma unroll
        for (int w = 0; w < 8; ++w) s += s_w[w];
        atomicAdd(&ctrl->accum, s);
        atomicAdd(&ctrl->count, T * (T - 1) / 2);
        __threadfence();        // order accum/count before done2
        const int prev2 = atomicAdd(&ctrl->done2, 1);
        if (prev2 == BSZ - 1) {
            const float sum = atomicAdd(&ctrl->accum, 0.0f);
            const int   c   = atomicAdd(&ctrl->count, 0);
            out[0] = sum / (float)(c > 1 ? c : 1);
        }
    }
}

extern "C" void kernel_launch(void* const* d_in, const int* in_sizes, int n_in,
                              void* d_out, int out_size, void* d_ws, size_t ws_size,
                              hipStream_t stream) {
    const float* enc  = (const float*)d_in[0];  // [BSZ, LMAX, DIM] fp32
    const int*   mask = (const int*)d_in[1];    // [BSZ, LMAX] int32
    const float* W    = (const float*)d_in[2];  // [2*DIM, 2] fp32
    const float* bias = (const float*)d_in[3];  // [2] fp32
    float* out = (float*)d_out;

    float* proj = (float*)d_ws;                          // 8192 float4 = 128 KB
    Ctrl*  ctrl = (Ctrl*)((char*)d_ws + BSZ * LMAX * 16);

    hipMemsetAsync(ctrl, 0, sizeof(Ctrl), stream);       // 272 B, graph-legal
    fused_kernel<<<(BSZ * LMAX) / 8, 512, 0, stream>>>(
        enc, W, mask, bias, proj, ctrl, out);
}

// Round 6
// 28.485 us; speedup vs baseline: 8.6450x; 8.6450x over previous
//
#include <hip/hip_runtime.h>

#define BSZ 64
#define LMAX 128
#define DIM 2048

struct Ctrl {
    float accum;   // loss sum
    int   count;   // valid-pair count
    int   done2;   // finished loss-blocks
};

// ---------------- kernel 1: projections (+ ctrl init) ----------------
// 1024 blocks x 512 threads; 8 waves/block, 1 position/wave.
// W (32 KB) staged per block into LDS as 4 SoA float4 arrays.
// NO device-scope fences anywhere — kernel boundary is the sync.
__global__ __launch_bounds__(512) void proj_kernel(
        const float* __restrict__ enc,
        const float* __restrict__ W,
        float* __restrict__ proj,
        Ctrl* __restrict__ ctrl) {
    if (blockIdx.x == 0 && threadIdx.x == 0) {
        ctrl->accum = 0.0f;
        ctrl->count = 0;
        ctrl->done2 = 0;
    }

    __shared__ float4 sW[4][512];

    const float4* __restrict__ W4 = (const float4*)W;   // [2*DIM, 2] row-major
    {
        const int i = threadIdx.x;
        sW[0][i] = W4[i * 2];
        sW[1][i] = W4[i * 2 + 1];
        sW[2][i] = W4[1024 + i * 2];
        sW[3][i] = W4[1024 + i * 2 + 1];
    }
    __syncthreads();

    const int wid  = threadIdx.x >> 6;
    const int lane = threadIdx.x & 63;
    const int p    = blockIdx.x * 8 + wid;       // position 0..8191

    const float4* __restrict__ h4 = (const float4*)(enc + (size_t)p * DIM);

    float a0 = 0.f, a1 = 0.f, a2 = 0.f, a3 = 0.f;
    #pragma unroll
    for (int it = 0; it < 8; ++it) {
        const int idx = it * 64 + lane;
        const float4 h  = h4[idx];
        const float4 w0 = sW[0][idx];
        const float4 w1 = sW[1][idx];
        const float4 w2 = sW[2][idx];
        const float4 w3 = sW[3][idx];
        a0 += h.x * w0.x + h.y * w0.z + h.z * w1.x + h.w * w1.z;
        a1 += h.x * w0.y + h.y * w0.w + h.z * w1.y + h.w * w1.w;
        a2 += h.x * w2.x + h.y * w2.z + h.z * w3.x + h.w * w3.z;
        a3 += h.x * w2.y + h.y * w2.w + h.z * w3.y + h.w * w3.w;
    }
    #pragma unroll
    for (int off = 32; off >= 1; off >>= 1) {
        a0 += __shfl_xor(a0, off);
        a1 += __shfl_xor(a1, off);
        a2 += __shfl_xor(a2, off);
        a3 += __shfl_xor(a3, off);
    }
    if (lane == 0) {
        float4 v; v.x = a0; v.y = a1; v.z = a2; v.w = a3;
        ((float4*)proj)[p] = v;
    }
}

// ---------------- kernel 2: pairwise NLL + finalize ----------------
// 256 blocks x 256 threads; 4 blocks per batch, stride-partitioned pairs.
__global__ __launch_bounds__(256) void loss_kernel(
        const int* __restrict__ mask,
        const float* __restrict__ proj,
        const float* __restrict__ bias,
        Ctrl* __restrict__ ctrl,
        float* __restrict__ out) {
    __shared__ float4 s_proj[LMAX];
    __shared__ float  s_w[4];
    __shared__ int    s_m[4];

    const int b   = blockIdx.x >> 2;         // batch 0..63
    const int q   = blockIdx.x & 3;          // quarter 0..3
    const int tid = threadIdx.x;

    if (tid < LMAX) s_proj[tid] = ((const float4*)proj)[b * LMAX + tid];

    int m = (tid < LMAX) ? mask[b * LMAX + tid] : 0;
    #pragma unroll
    for (int off = 32; off >= 1; off >>= 1) m += __shfl_xor(m, off);
    if ((tid & 63) == 0) s_m[tid >> 6] = m;
    __syncthreads();

    const int   T  = s_m[0] + s_m[1] + s_m[2] + s_m[3];
    const float b0 = bias[0];
    const float b1 = bias[1];

    float local = 0.f;
    const int tmax = T << 7;                 // T*128 candidate pairs
    for (int t = q * 256 + tid; t < tmax; t += 1024) {
        const int j = t >> 7;
        const int k = t & (LMAX - 1);
        if (k < j) {
            const float4 pj = s_proj[j];
            const float4 pk = s_proj[k];
            const float l0 = pj.x + pk.z + b0;
            const float l1 = pj.y + pk.w + b1;
            const bool  pos = (k == j - 1);
            const float d  = pos ? (l0 - l1) : (l1 - l0);
            local += fmaxf(d, 0.f) + __logf(1.f + __expf(-fabsf(d)));
        }
    }

    #pragma unroll
    for (int off = 32; off >= 1; off >>= 1) local += __shfl_xor(local, off);
    if ((tid & 63) == 0) s_w[tid >> 6] = local;
    __syncthreads();

    if (tid == 0) {
        atomicAdd(&ctrl->accum, s_w[0] + s_w[1] + s_w[2] + s_w[3]);
        if (q == 0) atomicAdd(&ctrl->count, T * (T - 1) / 2);
        __threadfence();                     // order partials before ticket (64+256 fences total, loss only)
        const int prev = atomicAdd(&ctrl->done2, 1);
        if (prev == 4 * BSZ - 1) {
            const float s = atomicAdd(&ctrl->accum, 0.0f);
            const int   c = atomicAdd(&ctrl->count, 0);
            out[0] = s / (float)(c > 1 ? c : 1);
        }
    }
}

extern "C" void kernel_launch(void* const* d_in, const int* in_sizes, int n_in,
                              void* d_out, int out_size, void* d_ws, size_t ws_size,
                              hipStream_t stream) {
    const float* enc  = (const float*)d_in[0];  // [BSZ, LMAX, DIM] fp32
    const int*   mask = (const int*)d_in[1];    // [BSZ, LMAX] int32
    const float* W    = (const float*)d_in[2];  // [2*DIM, 2] fp32
    const float* bias = (const float*)d_in[3];  // [2] fp32
    float* out = (float*)d_out;

    float* proj = (float*)d_ws;                          // 8192 float4 = 128 KB
    Ctrl*  ctrl = (Ctrl*)((char*)d_ws + BSZ * LMAX * 16);

    proj_kernel<<<(BSZ * LMAX) / 8, 512, 0, stream>>>(enc, W, proj, ctrl);
    loss_kernel<<<4 * BSZ, 256, 0, stream>>>(mask, proj, bias, ctrl, out);
}

// Round 7
// 27.419 us; speedup vs baseline: 8.9811x; 1.0389x over previous
//
#include <hip/hip_runtime.h>

#define BSZ 64
#define LMAX 128
#define DIM 2048
#define NPOS (BSZ * LMAX)   // 8192

struct Ctrl {
    float accum;   // loss sum
    int   count;   // valid-pair count
    int   done2;   // finished loss-blocks
};

// ---------------- kernel 1: projections (+ ctrl init) ----------------
// 512 blocks x 512 threads = 8 waves. Wave-pair owns 4 positions; each wave
// covers half a row (1024 dims) with its W-slice held in REGISTERS (16 float4,
// loaded once from L2). No LDS. Halves write separate proj buffers; the loss
// kernel sums them. Reduction: 2-step acc-fold + 4-step butterfly (6 shfl/pos).
__global__ __launch_bounds__(512, 4) void proj_kernel(
        const float* __restrict__ enc,
        const float* __restrict__ W,
        float* __restrict__ proj,      // [2][NPOS][4] floats
        Ctrl* __restrict__ ctrl) {
    if (blockIdx.x == 0 && threadIdx.x == 0) {
        ctrl->accum = 0.f; ctrl->count = 0; ctrl->done2 = 0;
    }

    const int tid  = threadIdx.x;
    const int wid  = tid >> 6;
    const int lane = tid & 63;
    const int pair = wid >> 1;                      // 0..3
    const int half = wid & 1;                       // 0..1
    const int p0   = blockIdx.x * 16 + pair * 4;    // first of 4 positions

    // ---- W slice into registers: idx(it) = half*256 + it*64 + lane ----
    const float4* __restrict__ W4 = (const float4*)W;   // [2*DIM,2] row-major
    float4 wl0[4], wl1[4], wr0[4], wr1[4];
    #pragma unroll
    for (int it = 0; it < 4; ++it) {
        const int idx = half * 256 + it * 64 + lane;
        wl0[it] = W4[idx * 2];
        wl1[it] = W4[idx * 2 + 1];
        wr0[it] = W4[1024 + idx * 2];
        wr1[it] = W4[1024 + idx * 2 + 1];
    }

    float a0[4], a1[4], a2[4], a3[4];
    #pragma unroll
    for (int q = 0; q < 4; ++q) { a0[q] = a1[q] = a2[q] = a3[q] = 0.f; }

    const float4* __restrict__ h4 = (const float4*)enc;
    const size_t base = (size_t)p0 * (DIM / 4) + half * 256 + lane;

    // prefetch position 0
    float4 hq[4];
    #pragma unroll
    for (int it = 0; it < 4; ++it) hq[it] = h4[base + it * 64];

    #pragma unroll
    for (int q = 0; q < 4; ++q) {
        float4 hn[4];
        if (q < 3) {
            #pragma unroll
            for (int it = 0; it < 4; ++it)
                hn[it] = h4[base + (size_t)(q + 1) * (DIM / 4) + it * 64];
        }
        #pragma unroll
        for (int it = 0; it < 4; ++it) {
            const float4 h = hq[it];
            a0[q] += h.x * wl0[it].x + h.y * wl0[it].z + h.z * wl1[it].x + h.w * wl1[it].z;
            a1[q] += h.x * wl0[it].y + h.y * wl0[it].w + h.z * wl1[it].y + h.w * wl1[it].w;
            a2[q] += h.x * wr0[it].x + h.y * wr0[it].z + h.z * wr1[it].x + h.w * wr1[it].z;
            a3[q] += h.x * wr0[it].y + h.y * wr0[it].w + h.z * wr1[it].y + h.w * wr1[it].w;
        }
        if (q < 3) {
            #pragma unroll
            for (int it = 0; it < 4; ++it) hq[it] = hn[it];
        }
    }

    // ---- reduce: fold 4 accs into lane residue (2 shfl-steps), then butterfly ----
    float* __restrict__ projf = proj + (size_t)half * NPOS * 4;
    #pragma unroll
    for (int q = 0; q < 4; ++q) {
        const bool o1 = (lane & 1);
        const float r1 = __shfl_xor(o1 ? a0[q] : a1[q], 1);
        float s = (o1 ? a1[q] : a0[q]) + r1;        // even: a0-pair, odd: a1-pair
        const float r2 = __shfl_xor(o1 ? a2[q] : a3[q], 1);
        float t = (o1 ? a3[q] : a2[q]) + r2;        // even: a2-pair, odd: a3-pair
        const bool o2 = (lane & 2);
        const float r3 = __shfl_xor(o2 ? s : t, 2);
        float u = (o2 ? t : s) + r3;                // residue lane&3 -> acc_{lane&3}
        u += __shfl_xor(u, 4);
        u += __shfl_xor(u, 8);
        u += __shfl_xor(u, 16);
        u += __shfl_xor(u, 32);
        if (lane < 4) projf[(size_t)(p0 + q) * 4 + lane] = u;
    }
}

// ---------------- kernel 2: pairwise NLL + finalize ----------------
// 256 blocks x 256 threads; 4 blocks per batch; sums the two proj halves.
__global__ __launch_bounds__(256) void loss_kernel(
        const int* __restrict__ mask,
        const float* __restrict__ proj,
        const float* __restrict__ bias,
        Ctrl* __restrict__ ctrl,
        float* __restrict__ out) {
    __shared__ float4 s_proj[LMAX];
    __shared__ float  s_w[4];
    __shared__ int    s_m[4];

    const int b   = blockIdx.x >> 2;
    const int q   = blockIdx.x & 3;
    const int tid = threadIdx.x;

    const float4* proj4 = (const float4*)proj;
    if (tid < LMAX) {
        const float4 pa = proj4[b * LMAX + tid];
        const float4 pb = proj4[NPOS + b * LMAX + tid];
        float4 v;
        v.x = pa.x + pb.x; v.y = pa.y + pb.y;
        v.z = pa.z + pb.z; v.w = pa.w + pb.w;
        s_proj[tid] = v;
    }

    int m = (tid < LMAX) ? mask[b * LMAX + tid] : 0;
    #pragma unroll
    for (int off = 32; off >= 1; off >>= 1) m += __shfl_xor(m, off);
    if ((tid & 63) == 0) s_m[tid >> 6] = m;
    __syncthreads();

    const int   T  = s_m[0] + s_m[1] + s_m[2] + s_m[3];
    const float b0 = bias[0];
    const float b1 = bias[1];

    float local = 0.f;
    const int tmax = T << 7;
    for (int t = q * 256 + tid; t < tmax; t += 1024) {
        const int j = t >> 7;
        const int k = t & (LMAX - 1);
        if (k < j) {
            const float4 pj = s_proj[j];
            const float4 pk = s_proj[k];
            const float l0 = pj.x + pk.z + b0;
            const float l1 = pj.y + pk.w + b1;
            const bool  pos = (k == j - 1);
            const float d  = pos ? (l0 - l1) : (l1 - l0);
            local += fmaxf(d, 0.f) + __logf(1.f + __expf(-fabsf(d)));
        }
    }

    #pragma unroll
    for (int off = 32; off >= 1; off >>= 1) local += __shfl_xor(local, off);
    if ((tid & 63) == 0) s_w[tid >> 6] = local;
    __syncthreads();

    if (tid == 0) {
        atomicAdd(&ctrl->accum, s_w[0] + s_w[1] + s_w[2] + s_w[3]);
        if (q == 0) atomicAdd(&ctrl->count, T * (T - 1) / 2);
        __threadfence();
        const int prev = atomicAdd(&ctrl->done2, 1);
        if (prev == 4 * BSZ - 1) {
            const float s = atomicAdd(&ctrl->accum, 0.0f);
            const int   c = atomicAdd(&ctrl->count, 0);
            out[0] = s / (float)(c > 1 ? c : 1);
        }
    }
}

extern "C" void kernel_launch(void* const* d_in, const int* in_sizes, int n_in,
                              void* d_out, int out_size, void* d_ws, size_t ws_size,
                              hipStream_t stream) {
    const float* enc  = (const float*)d_in[0];  // [BSZ, LMAX, DIM] fp32
    const int*   mask = (const int*)d_in[1];    // [BSZ, LMAX] int32
    const float* W    = (const float*)d_in[2];  // [2*DIM, 2] fp32
    const float* bias = (const float*)d_in[3];  // [2] fp32
    float* out = (float*)d_out;

    float* proj = (float*)d_ws;                          // 2*NPOS float4 = 256 KB
    Ctrl*  ctrl = (Ctrl*)((char*)d_ws + 2 * NPOS * 16);

    proj_kernel<<<NPOS / 16, 512, 0, stream>>>(enc, W, proj, ctrl);
    loss_kernel<<<4 * BSZ, 256, 0, stream>>>(mask, proj, bias, ctrl, out);
}